// Round 15
// baseline (106.813 us; speedup 1.0000x reference)
//
#include <hip/hip_runtime.h>
#include <hip/hip_bf16.h>
#include <stdint.h>

#define BATCH   512
#define INCH    20
#define FEAT    128
#define KACT    16
#define NUNIT   12

typedef short bf16x8 __attribute__((ext_vector_type(8)));
typedef float f32x4  __attribute__((ext_vector_type(4)));
typedef float f32x16 __attribute__((ext_vector_type(16)));

// Wpack: [ky][ks][h][f][8]; k = ks*16 + h*8 + j -> (kx=k/20, c=k%20), 0 for k>=60.
// Storage row m=f&31 computes model feature (f&~31) + phi(m), phi(e+4h'+8q)=e+4q+16h'
// (so each lane's 16 outputs are feature-contiguous in the epilogue).
#define WPACK_ELEMS (3*4*2*128*8)
#define WHEAD_ELEMS (4*4*4*16*8)    // [agent][kt][g][action][j], f = kt*32+g*8+j

#define XIN_ROWS  10                       // padded rows y0-1 .. y0+8
#define XIN_ELEMS (XIN_ROWS*34*20 + 64)    // + slack for k>=60 overreads (stays zero)

__device__ __forceinline__ uint16_t f2bf(float f) {
    union { float f; uint32_t u; } x{f};
    uint32_t u = x.u;
    return (uint16_t)((u + 0x7FFFu + ((u >> 16) & 1u)) >> 16);  // RNE
}

__device__ __forceinline__ uint32_t cvt_pk_bf16(float lo, float hi) {
    uint32_t r;
    asm("v_cvt_pk_bf16_f32 %0, %1, %2" : "=v"(r) : "v"(lo), "v"(hi));
    return r;
}

// lgkm-only barrier: only LDS ordering needed across the per-step barrier.
__device__ __forceinline__ void lds_barrier() {
    asm volatile("s_waitcnt lgkmcnt(0)\n\ts_barrier" ::: "memory");
}

// ---- One-time weight repack (fp32 -> bf16 fragment order) ----
__global__ void repack_kernel(const float* __restrict__ conv_w,
                              const float* __restrict__ W_all,
                              uint16_t* __restrict__ Wpack,
                              uint16_t* __restrict__ Whead) {
    int idx = blockIdx.x * 256 + threadIdx.x;
    if (idx < WPACK_ELEMS) {
        int j = idx & 7, t = idx >> 3;
        int f = t & 127; t >>= 7;
        int h = t & 1;   t >>= 1;
        int ks = t & 3;  int ky = t >> 2;
        int k = ks * 16 + h * 8 + j;
        float v = 0.0f;
        if (k < 60) {
            int kx = k / 20, c = k % 20;
            // feature permutation: m = f&31 = e + 4h' + 8q  ->  F = e + 4q + 16h'
            int m  = f & 31;
            int F  = (f & ~31) + (m & 3) + 4 * ((m >> 3) & 3) + 16 * ((m >> 2) & 1);
            v = conv_w[((F * INCH + c) * 3 + ky) * 3 + kx];
        }
        Wpack[idx] = f2bf(v);
    } else if (idx < WPACK_ELEMS + WHEAD_ELEMS) {
        int i = idx - WPACK_ELEMS;
        int j = i & 7, t = i >> 3;
        int a = t & 15; t >>= 4;
        int g = t & 3;  t >>= 2;
        int kt = t & 3; int ag = t >> 2;
        int f = kt * 32 + g * 8 + j;
        Whead[i] = f2bf(W_all[(ag * KACT + a) * FEAT + f]);
    }
}

// ---- Fused conv3x3 + relu/bias/mask + per-sample head GEMM ----
// Quarter-sample blocks (2048 x 256 thr = 4 fq-waves), 4 blocks/CU, 4 w/SIMD.
// Conv = 32x32x16 MFMA: one wave covers 32 pos x 32 feats in 12 MFMAs (vs 24
// 16x16x32) with the same 12 b128 LDS reads and the same 48-reg Wc. lane=pos
// C/D layout: 1 mask scalar/lane, bias preloaded in acc init, and the feature
// permutation makes the epilogue 2 x ds_write_b128. Head (16x16x32) + xl
// double buffer + lgkm-only barrier + setprio unchanged from R9/R14.
__global__ __launch_bounds__(256, 4) void fused_mfma_kernel(
    const float* __restrict__ states,    // [512,20,32,32]
    const int*   __restrict__ labels,    // [512]
    const float* __restrict__ maskings,  // [512,1,32,32]
    const float* __restrict__ conv_b,    // [128]
    const float* __restrict__ b_all,     // [4,16]
    const uint16_t* __restrict__ Wpack,
    const uint16_t* __restrict__ Whead,
    float*       __restrict__ out)       // [512*1024*12] ++ [512*1024*4]
{
    __shared__ __align__(16) uint16_t xin[XIN_ELEMS];    // 13,728 B
    __shared__ __align__(16) uint16_t xl[2 * 32 * 128];  // 16,384 B [buf][pos][feat]

    const int bid  = blockIdx.x;
    const int b    = bid >> 2;
    const int y0   = (bid & 3) << 3;   // rows y0 .. y0+7
    const int tid  = threadIdx.x;
    const int lane = tid & 63;
    const int fq   = tid >> 6;     // 0..3 : feature quarter (feats fq*32..+31)
    const int l31  = lane & 31;    // conv: position
    const int h    = lane >> 5;    // conv: k-half / feature-half-of-16
    const int l15  = lane & 15;
    const int g    = lane >> 4;    // head
    const int wswz = (l31 & 7) << 4;   // write swizzle (pos = l31)
    const int hswz = (l15 & 7) << 4;   // head read swizzle (pos&7 = l15&7)

    // ---- zero xin ----
    for (int i = tid; i < (XIN_ELEMS * 2) / 16; i += 256)
        ((uint4*)xin)[i] = uint4{0, 0, 0, 0};
    __syncthreads();

    // ---- stage xin rows r=0..9 (global y = y0+r-1) ----
    for (int t = 0; t < 7; ++t) {
        int i = t * 256 + tid;
        if (i < XIN_ROWS * 5 * 32) {
            int p  = i & 31;
            int tt = i >> 5;
            int cg = tt % 5;
            int r  = tt / 5;
            int y  = y0 + r - 1;
            if (y >= 0 && y < 32) {
                const float* sp = states + (size_t)b * (INCH * 1024) + cg * 4096 + y * 32 + p;
                float v0 = sp[0], v1 = sp[1024], v2 = sp[2048], v3 = sp[3072];
                uint64_t lo = cvt_pk_bf16(v0, v1);
                uint64_t hi = cvt_pk_bf16(v2, v3);
                *(uint64_t*)&xin[(r * 34 + p + 1) * 20 + cg * 4] = lo | (hi << 32);
            }
        }
    }

    // ---- per-lane invariants ----
    const int label = labels[b];

    // acc init = conv bias in permuted C/D layout: reg q*4+e, lane-h ->
    // F = fq*32 + 16h + 4q + e
    f32x16 accI;
    #pragma unroll
    for (int q = 0; q < 4; ++q) {
        f32x4 c4 = *(const f32x4*)&conv_b[fq * 32 + h * 16 + q * 4];
        #pragma unroll
        for (int e = 0; e < 4; ++e) accI[q * 4 + e] = c4[e];
    }

    const f32x4 hb = *(const f32x4*)&b_all[label * KACT + g * 4];  // actions g*4..+3
    bf16x8 Wh[4];                      // head A-frags: lane l15 = action, k = g*8+j
    #pragma unroll
    for (int kt = 0; kt < 4; ++kt)
        Wh[kt] = *(const bf16x8*)&Whead[(((label * 4 + kt) * 4 + g) * 16 + l15) * 8];

    // conv A-frags (weights), resident: [ky][ks] = 12 frags = 48 VGPRs
    bf16x8 Wc[3][4];
    #pragma unroll
    for (int ky = 0; ky < 3; ++ky)
        #pragma unroll
        for (int ks = 0; ks < 4; ++ks)
            Wc[ky][ks] = *(const bf16x8*)
                &Wpack[((((ky * 4 + ks) * 2 + h) * 128 + fq * 32 + l31) * 8)];

    const int hoff0 = (fq * 16 + l15) * 256;  // head read byte base (pos = fq*16+l15)
    const bool do_head = (fq < 2);

    __syncthreads();  // xin fully staged

    // ---- 8 steps; step s: row y = y0+s; one lgkm-only barrier per step ----
    #pragma unroll 2
    for (int s = 0; s < 8; ++s) {
        const int y = y0 + s;

        // mask for this lane's position (lane = pos)
        const float m = maskings[(size_t)b * 1024 + y * 32 + l31];

        f32x16 acc = accI;   // bias preloaded

        // conv: A = resident quarter-weights, B = im2col row from xin
        __builtin_amdgcn_s_setprio(1);
        #pragma unroll
        for (int ky = 0; ky < 3; ++ky) {
            const char* rbase = (const char*)xin + (((s + ky) * 34 + l31) * 20 + h * 8) * 2;
            #pragma unroll
            for (int ks = 0; ks < 4; ++ks) {
                bf16x8 X = *(const bf16x8*)(rbase + ks * 32);
                acc = __builtin_amdgcn_mfma_f32_32x32x16_bf16(Wc[ky][ks], X, acc, 0, 0, 0);
            }
        }
        __builtin_amdgcn_s_setprio(0);

        // epilogue: relu+mask (bias already in), pack, 2 x b128 swizzled writes
        char* xbase = (char*)xl + (s & 1) * 8192;
        #pragma unroll
        for (int q2 = 0; q2 < 2; ++q2) {
            float v0 = fmaxf(acc[q2 * 8 + 0], 0.f) * m;
            float v1 = fmaxf(acc[q2 * 8 + 1], 0.f) * m;
            float v2 = fmaxf(acc[q2 * 8 + 2], 0.f) * m;
            float v3 = fmaxf(acc[q2 * 8 + 3], 0.f) * m;
            float v4 = fmaxf(acc[q2 * 8 + 4], 0.f) * m;
            float v5 = fmaxf(acc[q2 * 8 + 5], 0.f) * m;
            float v6 = fmaxf(acc[q2 * 8 + 6], 0.f) * m;
            float v7 = fmaxf(acc[q2 * 8 + 7], 0.f) * m;
            uint4 pk;
            pk.x = cvt_pk_bf16(v0, v1);
            pk.y = cvt_pk_bf16(v2, v3);
            pk.z = cvt_pk_bf16(v4, v5);
            pk.w = cvt_pk_bf16(v6, v7);
            // feats F = fq*32 + 16h + 8*q2 + 0..7 at pos l31
            const int off = l31 * 256 + fq * 64 + h * 32 + q2 * 16;
            *(uint4*)(xbase + (off ^ wswz)) = pk;
        }

        lds_barrier();  // xl[s&1] complete; out-stores stay in flight

        // head: waves fq<2 do tile fq (pos = fq*16+l15); K=128 = 4 kt slices
        if (do_head) {
            f32x4 hacc = f32x4{0.f, 0.f, 0.f, 0.f};
            __builtin_amdgcn_s_setprio(1);
            #pragma unroll
            for (int kt = 0; kt < 4; ++kt) {
                const int off = hoff0 + kt * 64 + g * 16;
                bf16x8 bx = *(const bf16x8*)(xbase + (off ^ hswz));
                hacc = __builtin_amdgcn_mfma_f32_16x16x32_bf16(Wh[kt], bx, hacc, 0, 0, 0);
            }
            __builtin_amdgcn_s_setprio(0);
            const size_t pos = (size_t)b * 1024 + y * 32 + fq * 16 + l15;
            f32x4 o = hacc + hb;
            if (g < 3) *(f32x4*)&out[pos * NUNIT + g * 4] = o;                    // actions 0..11
            else       *(f32x4*)&out[(size_t)BATCH * 1024 * NUNIT + pos * 4] = o; // actions 12..15
        }
    }
}

extern "C" void kernel_launch(void* const* d_in, const int* in_sizes, int n_in,
                              void* d_out, int out_size, void* d_ws, size_t ws_size,
                              hipStream_t stream) {
    const float* states   = (const float*)d_in[0];
    const int*   labels   = (const int*)d_in[1];
    const float* maskings = (const float*)d_in[2];
    const float* conv_w   = (const float*)d_in[3];
    const float* conv_b   = (const float*)d_in[4];
    const float* W_all    = (const float*)d_in[5];
    const float* b_all    = (const float*)d_in[6];
    float* out = (float*)d_out;

    uint16_t* Wpack = (uint16_t*)d_ws;
    uint16_t* Whead = Wpack + WPACK_ELEMS;

    repack_kernel<<<(WPACK_ELEMS + WHEAD_ELEMS + 255) / 256, 256, 0, stream>>>(
        conv_w, W_all, Wpack, Whead);
    fused_mfma_kernel<<<BATCH * 4, 256, 0, stream>>>(
        states, labels, maskings, conv_b, b_all, Wpack, Whead, out);
}

// Round 16
// 89.927 us; speedup vs baseline: 1.1878x; 1.1878x over previous
//
#include <hip/hip_runtime.h>
#include <hip/hip_bf16.h>
#include <stdint.h>

#define BATCH   512
#define INCH    20
#define FEAT    128
#define KACT    16
#define NUNIT   12

typedef short bf16x8 __attribute__((ext_vector_type(8)));
typedef float f32x4  __attribute__((ext_vector_type(4)));
typedef float f32x16 __attribute__((ext_vector_type(16)));

// Wpack: [ky][ks][h][f][8]; k = ks*16 + h*8 + j -> (kx=k/20, c=k%20), 0 for k>=60.
// Feature permutation (verified R15): storage row m computes model feature
// (f&~31) + phi(m) so each lane's 16 conv outputs are feature-contiguous.
#define WPACK_ELEMS (3*4*2*128*8)
#define WHEAD_ELEMS (4*4*4*16*8)    // [agent][kt][g][action][j], f = kt*32+g*8+j

#define XIN_ROWS  10                       // padded rows y0-1 .. y0+8
#define XIN_ELEMS (XIN_ROWS*34*20 + 64)    // + slack for k>=60 overreads (stays zero)

__device__ __forceinline__ uint16_t f2bf(float f) {
    union { float f; uint32_t u; } x{f};
    uint32_t u = x.u;
    return (uint16_t)((u + 0x7FFFu + ((u >> 16) & 1u)) >> 16);  // RNE
}

__device__ __forceinline__ uint32_t cvt_pk_bf16(float lo, float hi) {
    uint32_t r;
    asm("v_cvt_pk_bf16_f32 %0, %1, %2" : "=v"(r) : "v"(lo), "v"(hi));
    return r;
}

// lgkm-only barrier: only LDS ordering needed across the per-step barrier.
__device__ __forceinline__ void lds_barrier() {
    asm volatile("s_waitcnt lgkmcnt(0)\n\ts_barrier" ::: "memory");
}

// ---- One-time weight repack (fp32 -> bf16 fragment order) ---- (R15, verified)
__global__ void repack_kernel(const float* __restrict__ conv_w,
                              const float* __restrict__ W_all,
                              uint16_t* __restrict__ Wpack,
                              uint16_t* __restrict__ Whead) {
    int idx = blockIdx.x * 256 + threadIdx.x;
    if (idx < WPACK_ELEMS) {
        int j = idx & 7, t = idx >> 3;
        int f = t & 127; t >>= 7;
        int h = t & 1;   t >>= 1;
        int ks = t & 3;  int ky = t >> 2;
        int k = ks * 16 + h * 8 + j;
        float v = 0.0f;
        if (k < 60) {
            int kx = k / 20, c = k % 20;
            int m  = f & 31;
            int F  = (f & ~31) + (m & 3) + 4 * ((m >> 3) & 3) + 16 * ((m >> 2) & 1);
            v = conv_w[((F * INCH + c) * 3 + ky) * 3 + kx];
        }
        Wpack[idx] = f2bf(v);
    } else if (idx < WPACK_ELEMS + WHEAD_ELEMS) {
        int i = idx - WPACK_ELEMS;
        int j = i & 7, t = i >> 3;
        int a = t & 15; t >>= 4;
        int g = t & 3;  t >>= 2;
        int kt = t & 3; int ag = t >> 2;
        int f = kt * 32 + g * 8 + j;
        Whead[i] = f2bf(W_all[(ag * KACT + a) * FEAT + f]);
    }
}

// ---- Fused conv3x3 + relu/bias/mask + per-sample head GEMM ----
// Quarter-sample blocks (2048 x 256 thr = 4 fq-waves), ~46 KB LDS -> 3
// blocks/CU at launch_bounds(256,3). 2 rows per step (4 steps, half the
// barriers): the 4 distinct im2col rows 2s..2s+3 are each read ONCE (16 b128
// vs 24) and feed 24 32x32x16 MFMAs split into TWO independent acc chains
// (fixes R15's fatal single 12-deep dependent chain). Epilogue/head/barrier
// machinery verified in R15/R9.
__global__ __launch_bounds__(256, 3) void fused_mfma_kernel(
    const float* __restrict__ states,    // [512,20,32,32]
    const int*   __restrict__ labels,    // [512]
    const float* __restrict__ maskings,  // [512,1,32,32]
    const float* __restrict__ conv_b,    // [128]
    const float* __restrict__ b_all,     // [4,16]
    const uint16_t* __restrict__ Wpack,
    const uint16_t* __restrict__ Whead,
    float*       __restrict__ out)       // [512*1024*12] ++ [512*1024*4]
{
    __shared__ __align__(16) uint16_t xin[XIN_ELEMS];    // 13,728 B
    __shared__ __align__(16) uint16_t xl[2 * 64 * 128];  // 32,768 B [buf][pos][feat]

    const int bid  = blockIdx.x;
    const int b    = bid >> 2;
    const int y0   = (bid & 3) << 3;   // rows y0 .. y0+7
    const int tid  = threadIdx.x;
    const int lane = tid & 63;
    const int fq   = tid >> 6;     // 0..3 : feature quarter (feats fq*32..+31)
    const int l31  = lane & 31;    // conv: position
    const int h    = lane >> 5;    // conv: k-half / feature-half-of-16
    const int l15  = lane & 15;
    const int g    = lane >> 4;    // head
    const int wswz = (l31 & 7) << 4;   // write swizzle (pos&7 = l31&7)
    const int hswz = (l15 & 7) << 4;   // head read swizzle (pos&7 = l15&7)

    // ---- zero xin ----
    for (int i = tid; i < (XIN_ELEMS * 2) / 16; i += 256)
        ((uint4*)xin)[i] = uint4{0, 0, 0, 0};
    __syncthreads();

    // ---- stage xin rows r=0..9 (global y = y0+r-1) ----
    for (int t = 0; t < 7; ++t) {
        int i = t * 256 + tid;
        if (i < XIN_ROWS * 5 * 32) {
            int p  = i & 31;
            int tt = i >> 5;
            int cg = tt % 5;
            int r  = tt / 5;
            int y  = y0 + r - 1;
            if (y >= 0 && y < 32) {
                const float* sp = states + (size_t)b * (INCH * 1024) + cg * 4096 + y * 32 + p;
                float v0 = sp[0], v1 = sp[1024], v2 = sp[2048], v3 = sp[3072];
                uint64_t lo = cvt_pk_bf16(v0, v1);
                uint64_t hi = cvt_pk_bf16(v2, v3);
                *(uint64_t*)&xin[(r * 34 + p + 1) * 20 + cg * 4] = lo | (hi << 32);
            }
        }
    }

    // ---- per-lane invariants ----
    const int label = labels[b];

    // acc init = conv bias in permuted C/D layout (R15, verified)
    f32x16 accI;
    #pragma unroll
    for (int q = 0; q < 4; ++q) {
        f32x4 c4 = *(const f32x4*)&conv_b[fq * 32 + h * 16 + q * 4];
        #pragma unroll
        for (int e = 0; e < 4; ++e) accI[q * 4 + e] = c4[e];
    }

    const f32x4 hb = *(const f32x4*)&b_all[label * KACT + g * 4];  // actions g*4..+3
    bf16x8 Wh[4];                      // head A-frags: lane l15 = action, k = g*8+j
    #pragma unroll
    for (int kt = 0; kt < 4; ++kt)
        Wh[kt] = *(const bf16x8*)&Whead[(((label * 4 + kt) * 4 + g) * 16 + l15) * 8];

    // conv A-frags (weights), resident: [ky][ks] = 12 frags = 48 VGPRs
    bf16x8 Wc[3][4];
    #pragma unroll
    for (int ky = 0; ky < 3; ++ky)
        #pragma unroll
        for (int ks = 0; ks < 4; ++ks)
            Wc[ky][ks] = *(const bf16x8*)
                &Wpack[((((ky * 4 + ks) * 2 + h) * 128 + fq * 32 + l31) * 8)];

    const int hoff0 = (fq * 16 + l15) * 256;  // head read byte base (pos = fq*16+l15)

    __syncthreads();  // xin fully staged

    // ---- 4 steps; step s: rows y0+2s, y0+2s+1; one lgkm barrier per step ----
    #pragma unroll 2
    for (int s = 0; s < 4; ++s) {
        const float m0 = maskings[(size_t)b * 1024 + (y0 + 2 * s) * 32 + l31];
        const float m1 = maskings[(size_t)b * 1024 + (y0 + 2 * s + 1) * 32 + l31];

        f32x16 a0 = accI;   // row rr=0, bias preloaded
        f32x16 a1 = accI;   // row rr=1

        // conv: 4 distinct im2col rows read once; each feeds both acc chains
        __builtin_amdgcn_s_setprio(1);
        #pragma unroll
        for (int t = 0; t < 4; ++t) {
            const char* rbase = (const char*)xin + (((2 * s + t) * 34 + l31) * 20 + h * 8) * 2;
            bf16x8 X[4];
            #pragma unroll
            for (int ks = 0; ks < 4; ++ks)
                X[ks] = *(const bf16x8*)(rbase + ks * 32);
            // rr=0 uses ky=t (t<3); rr=1 uses ky=t-1 (t>0) — interleaved chains
            #pragma unroll
            for (int ks = 0; ks < 4; ++ks) {
                if (t < 3)
                    a0 = __builtin_amdgcn_mfma_f32_32x32x16_bf16(Wc[t][ks], X[ks], a0, 0, 0, 0);
                if (t > 0)
                    a1 = __builtin_amdgcn_mfma_f32_32x32x16_bf16(Wc[t - 1][ks], X[ks], a1, 0, 0, 0);
            }
        }
        __builtin_amdgcn_s_setprio(0);

        // epilogue: relu+mask, pack, 2 x b128 swizzled writes per row
        char* xbase = (char*)xl + (s & 1) * 16384;
        #pragma unroll
        for (int rr = 0; rr < 2; ++rr) {
            const f32x16 A = rr ? a1 : a0;
            const float m  = rr ? m1 : m0;
            const int   p  = rr * 32 + l31;
            #pragma unroll
            for (int q2 = 0; q2 < 2; ++q2) {
                float v0 = fmaxf(A[q2 * 8 + 0], 0.f) * m;
                float v1 = fmaxf(A[q2 * 8 + 1], 0.f) * m;
                float v2 = fmaxf(A[q2 * 8 + 2], 0.f) * m;
                float v3 = fmaxf(A[q2 * 8 + 3], 0.f) * m;
                float v4 = fmaxf(A[q2 * 8 + 4], 0.f) * m;
                float v5 = fmaxf(A[q2 * 8 + 5], 0.f) * m;
                float v6 = fmaxf(A[q2 * 8 + 6], 0.f) * m;
                float v7 = fmaxf(A[q2 * 8 + 7], 0.f) * m;
                uint4 pk;
                pk.x = cvt_pk_bf16(v0, v1);
                pk.y = cvt_pk_bf16(v2, v3);
                pk.z = cvt_pk_bf16(v4, v5);
                pk.w = cvt_pk_bf16(v6, v7);
                const int off = p * 256 + fq * 64 + h * 32 + q2 * 16;
                *(uint4*)(xbase + (off ^ wswz)) = pk;
            }
        }

        lds_barrier();  // xl[s&1] complete; out-stores stay in flight

        // head: all 4 waves; wave fq does pos tile fq (16 pos); K=128 = 4 kt
        {
            f32x4 hacc = f32x4{0.f, 0.f, 0.f, 0.f};
            __builtin_amdgcn_s_setprio(1);
            #pragma unroll
            for (int kt = 0; kt < 4; ++kt) {
                const int off = hoff0 + kt * 64 + g * 16;
                bf16x8 bx = *(const bf16x8*)(xbase + (off ^ hswz));
                hacc = __builtin_amdgcn_mfma_f32_16x16x32_bf16(Wh[kt], bx, hacc, 0, 0, 0);
            }
            __builtin_amdgcn_s_setprio(0);
            const int y = y0 + 2 * s + (fq >> 1);
            const size_t pos = (size_t)b * 1024 + y * 32 + (fq & 1) * 16 + l15;
            f32x4 o = hacc + hb;
            if (g < 3) *(f32x4*)&out[pos * NUNIT + g * 4] = o;                    // actions 0..11
            else       *(f32x4*)&out[(size_t)BATCH * 1024 * NUNIT + pos * 4] = o; // actions 12..15
        }
    }
}

extern "C" void kernel_launch(void* const* d_in, const int* in_sizes, int n_in,
                              void* d_out, int out_size, void* d_ws, size_t ws_size,
                              hipStream_t stream) {
    const float* states   = (const float*)d_in[0];
    const int*   labels   = (const int*)d_in[1];
    const float* maskings = (const float*)d_in[2];
    const float* conv_w   = (const float*)d_in[3];
    const float* conv_b   = (const float*)d_in[4];
    const float* W_all    = (const float*)d_in[5];
    const float* b_all    = (const float*)d_in[6];
    float* out = (float*)d_out;

    uint16_t* Wpack = (uint16_t*)d_ws;
    uint16_t* Whead = Wpack + WPACK_ELEMS;

    repack_kernel<<<(WPACK_ELEMS + WHEAD_ELEMS + 255) / 256, 256, 0, stream>>>(
        conv_w, W_all, Wpack, Whead);
    fused_mfma_kernel<<<BATCH * 4, 256, 0, stream>>>(
        states, labels, maskings, conv_b, b_all, Wpack, Whead, out);
}

// Round 17
// 42.624 us; speedup vs baseline: 2.5059x; 2.1098x over previous
//
#include <hip/hip_runtime.h>
#include <hip/hip_bf16.h>
#include <stdint.h>

#define BATCH   512
#define INCH    20
#define FEAT    128
#define KACT    16
#define NUNIT   12

typedef short bf16x8 __attribute__((ext_vector_type(8)));
typedef float f32x4  __attribute__((ext_vector_type(4)));

#define BPACK_ELEMS (3*2*4*128*8)   // [ky][kk][g][f][j], k = kk*32+g*8+j -> (kx=k/20, c=k%20), 0 for k>=60
#define WHEAD_ELEMS (4*4*4*16*8)    // [agent][kt][g][action][j], f = kt*32+g*8+j

#define XIN_ROWS  10                       // padded rows y0-1 .. y0+8
#define XIN_ELEMS (XIN_ROWS*34*20 + 64)    // + slack for k>=60 overreads (stays zero)

__device__ __forceinline__ uint16_t f2bf(float f) {
    union { float f; uint32_t u; } x{f};
    uint32_t u = x.u;
    return (uint16_t)((u + 0x7FFFu + ((u >> 16) & 1u)) >> 16);  // RNE
}

__device__ __forceinline__ uint32_t cvt_pk_bf16(float lo, float hi) {
    uint32_t r;
    asm("v_cvt_pk_bf16_f32 %0, %1, %2" : "=v"(r) : "v"(lo), "v"(hi));
    return r;
}

// lgkm-only barrier: only LDS ordering needed across the per-step barrier.
__device__ __forceinline__ void lds_barrier() {
    asm volatile("s_waitcnt lgkmcnt(0)\n\ts_barrier" ::: "memory");
}

// ---- One-time weight repack (fp32 -> bf16 fragment order) ---- (R9, verified)
__global__ void repack_kernel(const float* __restrict__ conv_w,
                              const float* __restrict__ W_all,
                              uint16_t* __restrict__ Bpack,
                              uint16_t* __restrict__ Whead) {
    int idx = blockIdx.x * 256 + threadIdx.x;
    if (idx < BPACK_ELEMS) {
        int j = idx & 7, t = idx >> 3;
        int f = t & 127; t >>= 7;
        int g = t & 3;   t >>= 2;
        int kk = t & 1;  int ky = t >> 1;
        int k = kk * 32 + g * 8 + j;
        float v = 0.0f;
        if (k < 60) {
            int kx = k / 20, c = k % 20;
            v = conv_w[((f * INCH + c) * 3 + ky) * 3 + kx];
        }
        Bpack[idx] = f2bf(v);
    } else if (idx < BPACK_ELEMS + WHEAD_ELEMS) {
        int i = idx - BPACK_ELEMS;
        int j = i & 7, t = i >> 3;
        int a = t & 15; t >>= 4;
        int g = t & 3;  t >>= 2;
        int kt = t & 3; int ag = t >> 2;
        int f = kt * 32 + g * 8 + j;
        Whead[i] = f2bf(W_all[(ag * KACT + a) * FEAT + f]);
    }
}

// ---- Fused conv3x3 + relu/bias/mask + per-sample head GEMM ----
// Quarter-sample blocks (2048 x 256 thr = 4 fq-waves, F=32/wave), 16x16x32
// MFMAs in 4 independent acc chains (R9/R14 verified structure). NEW: 2 rows
// per step — the 4 distinct im2col rows 2s..2s+3 are read ONCE each (16 b128
// per 2 rows vs R14's 24) and feed both rows' chains; barriers halve to
// 4/block. LDS 46.5 KB -> 3 blocks/CU (3 independent barrier groups/SIMD).
__global__ __launch_bounds__(256, 3) void fused_mfma_kernel(
    const float* __restrict__ states,    // [512,20,32,32]
    const int*   __restrict__ labels,    // [512]
    const float* __restrict__ maskings,  // [512,1,32,32]
    const float* __restrict__ conv_b,    // [128]
    const float* __restrict__ b_all,     // [4,16]
    const uint16_t* __restrict__ Bpack,
    const uint16_t* __restrict__ Whead,
    float*       __restrict__ out)       // [512*1024*12] ++ [512*1024*4]
{
    __shared__ __align__(16) uint16_t xin[XIN_ELEMS];    // 13,728 B
    __shared__ __align__(16) uint16_t xl[2 * 64 * 128];  // 32,768 B [buf][pos][feat]

    const int bid  = blockIdx.x;
    const int b    = bid >> 2;
    const int y0   = (bid & 3) << 3;   // rows y0 .. y0+7
    const int tid  = threadIdx.x;
    const int lane = tid & 63;
    const int fq   = tid >> 6;     // 0..3 : feature quarter (feats fq*32..+31)
    const int l15  = lane & 15;
    const int g    = lane >> 4;    // 0..3
    const int swz  = (l15 & 7) << 4;   // XOR swizzle (pos&7 == l15&7 on both sides)

    // ---- zero xin ----
    for (int i = tid; i < (XIN_ELEMS * 2) / 16; i += 256)
        ((uint4*)xin)[i] = uint4{0, 0, 0, 0};
    __syncthreads();

    // ---- stage xin rows r=0..9 (global y = y0+r-1) ----
    for (int t = 0; t < 7; ++t) {
        int i = t * 256 + tid;
        if (i < XIN_ROWS * 5 * 32) {
            int p  = i & 31;
            int tt = i >> 5;
            int cg = tt % 5;
            int r  = tt / 5;
            int y  = y0 + r - 1;
            if (y >= 0 && y < 32) {
                const float* sp = states + (size_t)b * (INCH * 1024) + cg * 4096 + y * 32 + p;
                float v0 = sp[0], v1 = sp[1024], v2 = sp[2048], v3 = sp[3072];
                uint64_t lo = cvt_pk_bf16(v0, v1);
                uint64_t hi = cvt_pk_bf16(v2, v3);
                *(uint64_t*)&xin[(r * 34 + p + 1) * 20 + cg * 4] = lo | (hi << 32);
            }
        }
    }

    // ---- per-lane invariants (R9's per-wave budget: Wc=48) ----
    const int label = labels[b];
    f32x4 cb[2];                       // conv bias: f = fq*32 + nt*16 + g*4 + j
    #pragma unroll
    for (int nt = 0; nt < 2; ++nt)
        cb[nt] = *(const f32x4*)&conv_b[fq * 32 + nt * 16 + g * 4];
    const f32x4 hb = *(const f32x4*)&b_all[label * KACT + g * 4];  // actions g*4..+3
    bf16x8 Wh[4];                      // head A-frags: lane l15 = action, k = g*8+j
    #pragma unroll
    for (int kt = 0; kt < 4; ++kt)
        Wh[kt] = *(const bf16x8*)&Whead[(((label * 4 + kt) * 4 + g) * 16 + l15) * 8];

    // conv A-frags for this wave's feature quarter: 12 frags = 48 VGPRs
    bf16x8 Wc[3][2][2];
    #pragma unroll
    for (int ky = 0; ky < 3; ++ky)
        #pragma unroll
        for (int kk = 0; kk < 2; ++kk)
            #pragma unroll
            for (int nt = 0; nt < 2; ++nt)
                Wc[ky][kk][nt] = *(const bf16x8*)
                    &Bpack[((((ky * 2 + kk) * 4 + g) * 128 + fq * 32 + nt * 16 + l15) * 8)];

    const int hoff0 = (fq * 16 + l15) * 256;  // head read byte base (pos = fq*16+l15)

    __syncthreads();  // xin fully staged

    // ---- 4 steps; step s: rows y0+2s, y0+2s+1; one lgkm barrier per step ----
    #pragma unroll 2
    for (int s = 0; s < 4; ++s) {
        // masks for both rows x both ptiles (issue early)
        float mk[2][2];
        #pragma unroll
        for (int rr = 0; rr < 2; ++rr)
            #pragma unroll
            for (int pt = 0; pt < 2; ++pt)
                mk[rr][pt] = maskings[(size_t)b * 1024 + (y0 + 2 * s + rr) * 32 + pt * 16 + l15];

        char* xbase = (char*)xl + (s & 1) * 16384;

        // conv + epi, ptiles sequential (pt=0 epi writes overlap pt=1 conv)
        __builtin_amdgcn_s_setprio(1);
        #pragma unroll
        for (int pt = 0; pt < 2; ++pt) {
            f32x4 a0[2], a1[2];   // rows rr=0, rr=1; [nt] -> 4 independent chains
            #pragma unroll
            for (int nt = 0; nt < 2; ++nt) {
                a0[nt] = f32x4{0.f, 0.f, 0.f, 0.f};
                a1[nt] = f32x4{0.f, 0.f, 0.f, 0.f};
            }

            // 4 distinct im2col rows, each read ONCE, feeding both row-chains
            #pragma unroll
            for (int t = 0; t < 4; ++t) {
                const uint64_t* ap = (const uint64_t*)
                    &xin[((2 * s + t) * 34 + pt * 16 + l15) * 20 + g * 8];
                union { uint64_t u[2]; bf16x8 v; } X0, X1;
                X0.u[0] = ap[0]; X0.u[1] = ap[1];
                X1.u[0] = ap[8]; X1.u[1] = ap[9];
                #pragma unroll
                for (int kk = 0; kk < 2; ++kk) {
                    const bf16x8 Xk = kk ? X1.v : X0.v;
                    #pragma unroll
                    for (int nt = 0; nt < 2; ++nt) {
                        if (t < 3)
                            a0[nt] = __builtin_amdgcn_mfma_f32_16x16x32_bf16(
                                Wc[t][kk][nt], Xk, a0[nt], 0, 0, 0);
                        if (t > 0)
                            a1[nt] = __builtin_amdgcn_mfma_f32_16x16x32_bf16(
                                Wc[t - 1][kk][nt], Xk, a1[nt], 0, 0, 0);
                    }
                }
            }

            // epilogue for this pt, both rows
            #pragma unroll
            for (int rr = 0; rr < 2; ++rr) {
                const float m = mk[rr][pt];
                #pragma unroll
                for (int nt = 0; nt < 2; ++nt) {
                    const f32x4 A = rr ? a1[nt] : a0[nt];
                    float x0 = fmaxf(A[0] + cb[nt][0], 0.f) * m;
                    float x1 = fmaxf(A[1] + cb[nt][1], 0.f) * m;
                    float x2 = fmaxf(A[2] + cb[nt][2], 0.f) * m;
                    float x3 = fmaxf(A[3] + cb[nt][3], 0.f) * m;
                    uint64_t pk = (uint64_t)cvt_pk_bf16(x0, x1)
                                | ((uint64_t)cvt_pk_bf16(x2, x3) << 32);
                    // pos = rr*32 + pt*16 + l15 ; feat byte = fq*64 + nt*32 + g*8
                    const int off = ((rr * 2 + pt) * 16 + l15) * 256 + fq * 64 + nt * 32 + g * 8;
                    *(uint64_t*)(xbase + (off ^ swz)) = pk;
                }
            }
        }
        __builtin_amdgcn_s_setprio(0);

        lds_barrier();  // xl[s&1] complete; out-stores stay in flight

        // head: all 4 waves; wave fq does pos tile fq (16 of 64); K=128 = 4 kt
        {
            f32x4 hacc = f32x4{0.f, 0.f, 0.f, 0.f};
            __builtin_amdgcn_s_setprio(1);
            #pragma unroll
            for (int kt = 0; kt < 4; ++kt) {
                const int off = hoff0 + kt * 64 + g * 16;
                bf16x8 bx = *(const bf16x8*)(xbase + (off ^ swz));
                hacc = __builtin_amdgcn_mfma_f32_16x16x32_bf16(Wh[kt], bx, hacc, 0, 0, 0);
            }
            __builtin_amdgcn_s_setprio(0);
            const int y = y0 + 2 * s + (fq >> 1);
            const size_t pos = (size_t)b * 1024 + y * 32 + (fq & 1) * 16 + l15;
            f32x4 o = hacc + hb;
            if (g < 3) *(f32x4*)&out[pos * NUNIT + g * 4] = o;                    // actions 0..11
            else       *(f32x4*)&out[(size_t)BATCH * 1024 * NUNIT + pos * 4] = o; // actions 12..15
        }
    }
}

extern "C" void kernel_launch(void* const* d_in, const int* in_sizes, int n_in,
                              void* d_out, int out_size, void* d_ws, size_t ws_size,
                              hipStream_t stream) {
    const float* states   = (const float*)d_in[0];
    const int*   labels   = (const int*)d_in[1];
    const float* maskings = (const float*)d_in[2];
    const float* conv_w   = (const float*)d_in[3];
    const float* conv_b   = (const float*)d_in[4];
    const float* W_all    = (const float*)d_in[5];
    const float* b_all    = (const float*)d_in[6];
    float* out = (float*)d_out;

    uint16_t* Bpack = (uint16_t*)d_ws;
    uint16_t* Whead = Bpack + BPACK_ELEMS;

    repack_kernel<<<(BPACK_ELEMS + WHEAD_ELEMS + 255) / 256, 256, 0, stream>>>(
        conv_w, W_all, Bpack, Whead);
    fused_mfma_kernel<<<BATCH * 4, 256, 0, stream>>>(
        states, labels, maskings, conv_b, b_all, Bpack, Whead, out);
}